// Round 6
// baseline (420.085 us; speedup 1.0000x reference)
//
#include <hip/hip_runtime.h>

#define MM 4096
#define NN 4096
#define KK 4096
#define BM 128
#define BN 128
#define BK 32
#define NT (KK / BK)

typedef __attribute__((ext_vector_type(8))) _Float16 f16x8;
typedef __attribute__((ext_vector_type(2))) _Float16 f16x2;
typedef __attribute__((ext_vector_type(4))) float f32x4;

__device__ __forceinline__ f16x2 pk16(float a, float b) {
  return __builtin_bit_cast(f16x2, __builtin_amdgcn_cvt_pkrtz(a, b));
}

// Row stride is 64B at BK=32; bank period = 128B = 2 rows.
// Swizzle: byte(row,kb) = row*64 + (kb ^ (((row>>1)&3)<<4))
// -> slot(4..6 bits) uniform for all write/read patterns (derived per-instr).

__global__ __launch_bounds__(256, 4) void wq_gemm(
    const float* __restrict__ A, const int* __restrict__ Q,
    const float* __restrict__ S, const float* __restrict__ Z,
    float* __restrict__ C) {
  __shared__ __align__(16) _Float16 AsBuf[2][BM * BK];  // 8KB each
  __shared__ __align__(16) _Float16 BsBuf[2][BN * BK];  // 8KB each

  const int tid = threadIdx.x;
  const int lane = tid & 63;
  const int wid = tid >> 6;

  // bijective XCD swizzle (nwg=1024 % 8 == 0); m fast-varying
  const int nwg = (int)gridDim.x;
  const int bid0 = (int)blockIdx.x;
  const int wg = (bid0 & 7) * (nwg >> 3) + (bid0 >> 3);
  const int m0 = (wg & 31) * BM;
  const int n0 = (wg >> 5) * BN;

  // ---- A staging (fp32 -> fp16): thread owns row tid>>1, 16 k
  const int a_m = tid >> 1;
  const int a_k = (tid & 1) * 16;
  const float* a_src = A + (size_t)(m0 + a_m) * KK + a_k;
  int a_woff[2];
#pragma unroll
  for (int c = 0; c < 2; ++c)
    a_woff[c] = a_m * (BK * 2) + ((a_k * 2 + c * 16) ^ (((a_m >> 1) & 3) << 4));

  // ---- B staging: thread owns one n column, 16 consecutive k
  const int n_loc = tid & 127;
  const int kk0 = (tid >> 7) * 16;
  const int* q_src = Q + (size_t)kk0 * NN + (n0 + n_loc);
  const float* s_src = S + (n0 + n_loc);
  const float* z_src = Z + (n0 + n_loc);
  int bw_off[2];
#pragma unroll
  for (int c = 0; c < 2; ++c)
    bw_off[c] = n_loc * (BK * 2) + (((kk0 + c * 8) * 2) ^ (((n_loc >> 1) & 3) << 4));

  // ---- compute-side fragment addressing
  const int wm = wid >> 1, wn = wid & 1;
  const int lr = lane & 15, lg = lane >> 4;
  const int koffx = (lg * 16) ^ (((lr >> 1) & 3) << 4);
  int a_row[4], b_row[4];
#pragma unroll
  for (int f = 0; f < 4; ++f) {
    a_row[f] = (wm * 64 + f * 16 + lr) * (BK * 2);
    b_row[f] = (wn * 64 + f * 16 + lr) * (BK * 2);
  }

  f32x4 acc[4][4];
#pragma unroll
  for (int i = 0; i < 4; ++i)
#pragma unroll
    for (int j = 0; j < 4; ++j) acc[i][j] = (f32x4){0.f, 0.f, 0.f, 0.f};

  f32x4 av[4];
  int qv[16];
  float sf, bf;

  auto stage_load = [&](int t) {
    const float* ap = a_src + (size_t)t * BK;
#pragma unroll
    for (int p = 0; p < 4; ++p) av[p] = *(const f32x4*)(ap + p * 4);
    const int* qp = q_src + (size_t)t * BK * NN;
#pragma unroll
    for (int i = 0; i < 16; ++i) qv[i] = qp[(size_t)i * NN];
    const int g = t >> 2;  // GS=128 / BK=32
    sf = s_src[(size_t)g * NN];
    bf = -z_src[(size_t)g * NN] * sf;
  };

  auto stage_write = [&](int cb) {
    char* as = (char*)&AsBuf[cb][0];
#pragma unroll
    for (int c = 0; c < 2; ++c) {
      union { f16x2 h2[4]; f16x8 v; } u;
      f32x4 v0 = av[c * 2], v1 = av[c * 2 + 1];
      u.h2[0] = pk16(v0[0], v0[1]);
      u.h2[1] = pk16(v0[2], v0[3]);
      u.h2[2] = pk16(v1[0], v1[1]);
      u.h2[3] = pk16(v1[2], v1[3]);
      *(f16x8*)(as + a_woff[c]) = u.v;
    }
    char* bs = (char*)&BsBuf[cb][0];
#pragma unroll
    for (int c = 0; c < 2; ++c) {
      union { f16x2 h2[4]; f16x8 v; } u;
#pragma unroll
      for (int p = 0; p < 4; ++p) {
        float w0 = (float)qv[c * 8 + p * 2] * sf + bf;
        float w1 = (float)qv[c * 8 + p * 2 + 1] * sf + bf;
        u.h2[p] = pk16(w0, w1);
      }
      *(f16x8*)(bs + bw_off[c]) = u.v;
    }
  };

  // ================= prologue =================
  stage_load(0);
  stage_write(0);
  __syncthreads();

  // ================= main K loop =================
  for (int t = 0; t < NT; ++t) {
    const int c = t & 1;
    if (t + 1 < NT) stage_load(t + 1);  // global loads hide under MFMA

    {
      const char* as = (const char*)&AsBuf[c][0];
      const char* bs = (const char*)&BsBuf[c][0];
      f16x8 bfr[4];
#pragma unroll
      for (int j = 0; j < 4; ++j)
        bfr[j] = *(const f16x8*)(bs + (b_row[j] + koffx));
#pragma unroll
      for (int i = 0; i < 4; ++i) {
        f16x8 af = *(const f16x8*)(as + (a_row[i] + koffx));
#pragma unroll
        for (int j = 0; j < 4; ++j)
          acc[i][j] = __builtin_amdgcn_mfma_f32_16x16x32_f16(
              af, bfr[j], acc[i][j], 0, 0, 0);
      }
    }

    if (t + 1 < NT) stage_write(c ^ 1);
    __syncthreads();
  }

  // ================= epilogue: C/D col=lane&15, row=(lane>>4)*4+reg =================
#pragma unroll
  for (int i = 0; i < 4; ++i) {
    const int row0 = m0 + wm * 64 + i * 16 + lg * 4;
#pragma unroll
    for (int j = 0; j < 4; ++j) {
      const int col = n0 + wn * 64 + j * 16 + lr;
#pragma unroll
      for (int r = 0; r < 4; ++r)
        C[(size_t)(row0 + r) * NN + col] = acc[i][j][r];
    }
  }
}

extern "C" void kernel_launch(void* const* d_in, const int* in_sizes, int n_in,
                              void* d_out, int out_size, void* d_ws, size_t ws_size,
                              hipStream_t stream) {
  const float* A = (const float*)d_in[0];
  const int* Q = (const int*)d_in[1];
  const float* S = (const float*)d_in[2];
  const float* Z = (const float*)d_in[3];
  float* C = (float*)d_out;
  dim3 grid((MM / BM) * (NN / BN));
  dim3 block(256);
  wq_gemm<<<grid, block, 0, stream>>>(A, Q, S, Z, C);
}

// Round 7
// 264.604 us; speedup vs baseline: 1.5876x; 1.5876x over previous
//
#include <hip/hip_runtime.h>

#define MM 4096
#define NN 4096
#define KK 4096
#define BM 128
#define BN 128
#define BK 64
#define NT (KK / BK)

typedef __attribute__((ext_vector_type(8))) _Float16 f16x8;
typedef __attribute__((ext_vector_type(2))) _Float16 f16x2;
typedef __attribute__((ext_vector_type(4))) float f32x4;
typedef __attribute__((ext_vector_type(4))) int i32x4;

__device__ __forceinline__ f16x2 pk16(float a, float b) {
  return __builtin_bit_cast(f16x2, __builtin_amdgcn_cvt_pkrtz(a, b));
}

__device__ __forceinline__ void gload_lds16(const void* g, void* l) {
  __builtin_amdgcn_global_load_lds(
      (const __attribute__((address_space(1))) unsigned int*)g,
      (__attribute__((address_space(3))) unsigned int*)l, 16, 0, 0);
}

// ================= pre-pass 1: A fp32 -> fp16 =================
__global__ __launch_bounds__(256) void cvt_a(const float* __restrict__ A,
                                             _Float16* __restrict__ Ah) {
  const size_t i = ((size_t)blockIdx.x * 256 + threadIdx.x) * 8;
  f32x4 v0 = *(const f32x4*)(A + i);
  f32x4 v1 = *(const f32x4*)(A + i + 4);
  union { f16x2 h2[4]; f16x8 v; } u;
  u.h2[0] = pk16(v0[0], v0[1]);
  u.h2[1] = pk16(v0[2], v0[3]);
  u.h2[2] = pk16(v1[0], v1[1]);
  u.h2[3] = pk16(v1[2], v1[3]);
  *(f16x8*)(Ah + i) = u.v;
}

// ====== pre-pass 2: dequant Q[k][n] -> W^T[n][k] fp16 (64x64 LDS transpose) ======
__global__ __launch_bounds__(256) void deq_wt(const int* __restrict__ Q,
                                              const float* __restrict__ S,
                                              const float* __restrict__ Z,
                                              _Float16* __restrict__ WT) {
  __shared__ _Float16 T[64][72];  // [n][k], stride 144B (16B-aligned rows)
  const int tid = threadIdx.x;
  const int n0 = ((int)blockIdx.x & 63) * 64;
  const int k0 = ((int)blockIdx.x >> 6) * 64;
  const int g = k0 >> 7;  // GS=128, 64|k0 -> group constant per tile

  const int c4 = (tid & 15) * 4;
  f32x4 s4 = *(const f32x4*)(S + (size_t)g * NN + n0 + c4);
  f32x4 z4 = *(const f32x4*)(Z + (size_t)g * NN + n0 + c4);
#pragma unroll
  for (int p = 0; p < 4; ++p) {
    const int r = (tid >> 4) + p * 16;
    i32x4 q = *(const i32x4*)(Q + (size_t)(k0 + r) * NN + n0 + c4);
#pragma unroll
    for (int j = 0; j < 4; ++j)
      T[c4 + j][r] = (_Float16)(((float)q[j] - z4[j]) * s4[j]);
  }
  __syncthreads();
  const int n = tid >> 2;
  const int kc = (tid & 3) * 16;
  f16x8 w0 = *(const f16x8*)&T[n][kc];
  f16x8 w1 = *(const f16x8*)&T[n][kc + 8];
  _Float16* dst = WT + (size_t)(n0 + n) * KK + k0 + kc;
  *(f16x8*)dst = w0;
  *(f16x8*)(dst + 8) = w1;
}

// ================= main GEMM: m97 structure, both operands fp16 =================
__global__ __launch_bounds__(256, 2) void gemm16(const _Float16* __restrict__ Ah,
                                                 const _Float16* __restrict__ WT,
                                                 float* __restrict__ C) {
  __shared__ __align__(16) _Float16 AsBuf[2][BM * BK];  // linear [m][k]
  __shared__ __align__(16) _Float16 BsBuf[2][BN * BK];  // linear [n][k]

  const int tid = threadIdx.x;
  const int lane = tid & 63;
  const int wid = tid >> 6;

  // bijective XCD swizzle (nwg=1024 % 8 == 0); m fast-varying
  const int nwg = (int)gridDim.x;
  const int bid0 = (int)blockIdx.x;
  const int wg = (bid0 & 7) * (nwg >> 3) + (bid0 >> 3);
  const int m0 = (wg & 31) * BM;
  const int n0 = (wg >> 5) * BN;

  // staging: wave w, pass p covers rows p*32 + w*8 + (lane>>3), k-chunk (lane&7)*8
  const int st_row = wid * 8 + (lane >> 3);
  const int st_k = (lane & 7) * 8;
  const _Float16* a_src = Ah + (size_t)(m0 + st_row) * KK + st_k;
  const _Float16* b_src = WT + (size_t)(n0 + st_row) * KK + st_k;

  // compute-side fragment addressing (linear)
  const int wm = wid >> 1, wn = wid & 1;
  const int lr = lane & 15, lg = lane >> 4;
  int a_row[4], b_row[4], koff[2];
#pragma unroll
  for (int f = 0; f < 4; ++f) {
    a_row[f] = (wm * 64 + f * 16 + lr) * (BK * 2);
    b_row[f] = (wn * 64 + f * 16 + lr) * (BK * 2);
  }
#pragma unroll
  for (int ks = 0; ks < 2; ++ks)
    koff[ks] = (ks * 32 + lg * 8) * 2;

  f32x4 acc[4][4];
#pragma unroll
  for (int i = 0; i < 4; ++i)
#pragma unroll
    for (int j = 0; j < 4; ++j) acc[i][j] = (f32x4){0.f, 0.f, 0.f, 0.f};

  auto stage = [&](int c, int t) {
    char* abase = (char*)&AsBuf[c][0] + wid * 1024;
    char* bbase = (char*)&BsBuf[c][0] + wid * 1024;
    const _Float16* ap = a_src + (size_t)t * BK;
    const _Float16* bp = b_src + (size_t)t * BK;
#pragma unroll
    for (int p = 0; p < 4; ++p)
      gload_lds16(ap + (size_t)p * 32 * KK, abase + p * 4096);
#pragma unroll
    for (int p = 0; p < 4; ++p)
      gload_lds16(bp + (size_t)p * 32 * KK, bbase + p * 4096);
  };

  // prologue
  stage(0, 0);
  asm volatile("s_waitcnt vmcnt(0)" ::: "memory");
  __syncthreads();

  for (int t = 0; t < NT; ++t) {
    const int c = t & 1;
    if (t + 1 < NT) stage(c ^ 1, t + 1);  // DMA overlaps MFMA below

    {
      const char* as = (const char*)&AsBuf[c][0];
      const char* bs = (const char*)&BsBuf[c][0];
#pragma unroll
      for (int ks = 0; ks < 2; ++ks) {
        f16x8 af[4], bfr[4];
#pragma unroll
        for (int f = 0; f < 4; ++f) {
          af[f] = *(const f16x8*)(as + (a_row[f] + koff[ks]));
          bfr[f] = *(const f16x8*)(bs + (b_row[f] + koff[ks]));
        }
#pragma unroll
        for (int i = 0; i < 4; ++i)
#pragma unroll
          for (int j = 0; j < 4; ++j)
            acc[i][j] = __builtin_amdgcn_mfma_f32_16x16x32_f16(
                af[i], bfr[j], acc[i][j], 0, 0, 0);
      }
    }

    asm volatile("s_waitcnt vmcnt(0)" ::: "memory");
    __syncthreads();
  }

  // epilogue: C/D col=lane&15, row=(lane>>4)*4+reg
#pragma unroll
  for (int i = 0; i < 4; ++i) {
    const int row0 = m0 + wm * 64 + i * 16 + lg * 4;
#pragma unroll
    for (int j = 0; j < 4; ++j) {
      const int col = n0 + wn * 64 + j * 16 + lr;
#pragma unroll
      for (int r = 0; r < 4; ++r)
        C[(size_t)(row0 + r) * NN + col] = acc[i][j][r];
    }
  }
}

// ================= fallback: Round-5 fused kernel (proven, 360us) =================
__global__ __launch_bounds__(256, 2) void wq_gemm(
    const float* __restrict__ A, const int* __restrict__ Q,
    const float* __restrict__ S, const float* __restrict__ Z,
    float* __restrict__ C) {
  __shared__ __align__(16) _Float16 AsBuf[2][BM * BK];
  __shared__ __align__(16) _Float16 BsBuf[2][BN * BK];

  const int tid = threadIdx.x;
  const int lane = tid & 63;
  const int wid = tid >> 6;

  const int nwg = (int)gridDim.x;
  const int bid0 = (int)blockIdx.x;
  const int wg = (bid0 & 7) * (nwg >> 3) + (bid0 >> 3);
  const int m0 = (wg & 31) * BM;
  const int n0 = (wg >> 5) * BN;

  const int a_m = tid >> 3;
  const int a_k = (tid & 7) * 8;
  const float* a_src = A + (size_t)(m0 + a_m) * KK + a_k;
  const int a_woff = a_m * (BK * 2) + ((a_k * 2) ^ ((a_m & 7) << 4));

  const int n_loc = tid & 127;
  const int kk0 = (tid >> 7) * 32;
  const int* q_src = Q + (size_t)kk0 * NN + (n0 + n_loc);
  const float* s_src = S + (n0 + n_loc);
  const float* z_src = Z + (n0 + n_loc);
  int bw_off[4];
#pragma unroll
  for (int j = 0; j < 4; ++j)
    bw_off[j] = n_loc * (BK * 2) + (((kk0 + j * 8) * 2) ^ ((n_loc & 7) << 4));

  const int wm = wid >> 1, wn = wid & 1;
  const int lr = lane & 15, lg = lane >> 4;
  const int rx = (lr & 7) << 4;
  int a_row[4], b_row[4], koffx[2];
#pragma unroll
  for (int f = 0; f < 4; ++f) {
    a_row[f] = (wm * 64 + f * 16 + lr) * (BK * 2);
    b_row[f] = (wn * 64 + f * 16 + lr) * (BK * 2);
  }
#pragma unroll
  for (int ks = 0; ks < 2; ++ks)
    koffx[ks] = ((ks * 32 + lg * 8) * 2) ^ rx;

  f32x4 acc[4][4];
#pragma unroll
  for (int i = 0; i < 4; ++i)
#pragma unroll
    for (int j = 0; j < 4; ++j) acc[i][j] = (f32x4){0.f, 0.f, 0.f, 0.f};

  f32x4 av[8];
  int qv[32];
  float sf, bf;

  auto stage_load = [&](int t) {
    const float* ap = a_src + (size_t)t * BK;
#pragma unroll
    for (int p = 0; p < 4; ++p) {
      av[p * 2] = *(const f32x4*)(ap + (size_t)p * 32 * KK);
      av[p * 2 + 1] = *(const f32x4*)(ap + (size_t)p * 32 * KK + 4);
    }
    const int* qp = q_src + (size_t)t * BK * NN;
#pragma unroll
    for (int i = 0; i < 32; ++i) qv[i] = qp[(size_t)i * NN];
    const int g = t >> 1;
    sf = s_src[(size_t)g * NN];
    bf = -z_src[(size_t)g * NN] * sf;
  };

  auto stage_write = [&](int c) {
    char* as = (char*)&AsBuf[c][0];
#pragma unroll
    for (int p = 0; p < 4; ++p) {
      union { f16x2 h2[4]; f16x8 v; } u;
      f32x4 v0 = av[p * 2], v1 = av[p * 2 + 1];
      u.h2[0] = pk16(v0[0], v0[1]);
      u.h2[1] = pk16(v0[2], v0[3]);
      u.h2[2] = pk16(v1[0], v1[1]);
      u.h2[3] = pk16(v1[2], v1[3]);
      *(f16x8*)(as + a_woff + p * 4096) = u.v;
    }
    char* bs = (char*)&BsBuf[c][0];
#pragma unroll
    for (int j = 0; j < 4; ++j) {
      union { f16x2 h2[4]; f16x8 v; } u;
#pragma unroll
      for (int p = 0; p < 4; ++p) {
        float w0 = (float)qv[j * 8 + p * 2] * sf + bf;
        float w1 = (float)qv[j * 8 + p * 2 + 1] * sf + bf;
        u.h2[p] = pk16(w0, w1);
      }
      *(f16x8*)(bs + bw_off[j]) = u.v;
    }
  };

  stage_load(0);
  stage_write(0);
  __syncthreads();

  for (int t = 0; t < NT; ++t) {
    const int c = t & 1;
    if (t + 1 < NT) stage_load(t + 1);

    {
      const char* as = (const char*)&AsBuf[c][0];
      const char* bs = (const char*)&BsBuf[c][0];
#pragma unroll
      for (int ks = 0; ks < 2; ++ks) {
        f16x8 af[4], bfr[4];
#pragma unroll
        for (int f = 0; f < 4; ++f) {
          af[f] = *(const f16x8*)(as + (a_row[f] + koffx[ks]));
          bfr[f] = *(const f16x8*)(bs + (b_row[f] + koffx[ks]));
        }
#pragma unroll
        for (int i = 0; i < 4; ++i)
#pragma unroll
          for (int j = 0; j < 4; ++j)
            acc[i][j] = __builtin_amdgcn_mfma_f32_16x16x32_f16(
                af[i], bfr[j], acc[i][j], 0, 0, 0);
      }
    }

    if (t + 1 < NT) stage_write(c ^ 1);
    __syncthreads();
  }

#pragma unroll
  for (int i = 0; i < 4; ++i) {
    const int row0 = m0 + wm * 64 + i * 16 + lg * 4;
#pragma unroll
    for (int j = 0; j < 4; ++j) {
      const int col = n0 + wn * 64 + j * 16 + lr;
#pragma unroll
      for (int r = 0; r < 4; ++r)
        C[(size_t)(row0 + r) * NN + col] = acc[i][j][r];
    }
  }
}

extern "C" void kernel_launch(void* const* d_in, const int* in_sizes, int n_in,
                              void* d_out, int out_size, void* d_ws, size_t ws_size,
                              hipStream_t stream) {
  const float* A = (const float*)d_in[0];
  const int* Q = (const int*)d_in[1];
  const float* S = (const float*)d_in[2];
  const float* Z = (const float*)d_in[3];
  float* C = (float*)d_out;

  const size_t needA = (size_t)MM * KK * sizeof(_Float16);
  const size_t needW = (size_t)KK * NN * sizeof(_Float16);
  if (ws_size >= needA + needW) {
    _Float16* Ah = (_Float16*)d_ws;
    _Float16* WT = (_Float16*)((char*)d_ws + needA);
    cvt_a<<<dim3(MM * KK / (8 * 256)), dim3(256), 0, stream>>>(A, Ah);
    deq_wt<<<dim3((KK / 64) * (NN / 64)), dim3(256), 0, stream>>>(Q, S, Z, WT);
    gemm16<<<dim3((MM / BM) * (NN / BN)), dim3(256), 0, stream>>>(Ah, WT, C);
  } else {
    wq_gemm<<<dim3((MM / BM) * (NN / BN)), dim3(256), 0, stream>>>(A, Q, S, Z, C);
  }
}

// Round 8
// 221.408 us; speedup vs baseline: 1.8973x; 1.1951x over previous
//
#include <hip/hip_runtime.h>

#define MM 4096
#define NN 4096
#define KK 4096
#define BM 128
#define BN 128
#define BK 64
#define NT (KK / BK)

typedef __attribute__((ext_vector_type(8))) _Float16 f16x8;
typedef __attribute__((ext_vector_type(2))) _Float16 f16x2;
typedef __attribute__((ext_vector_type(4))) float f32x4;
typedef __attribute__((ext_vector_type(4))) int i32x4;

__device__ __forceinline__ f16x2 pk16(float a, float b) {
  return __builtin_bit_cast(f16x2, __builtin_amdgcn_cvt_pkrtz(a, b));
}

__device__ __forceinline__ void gload_lds16(const void* g, void* l) {
  __builtin_amdgcn_global_load_lds(
      (const __attribute__((address_space(1))) unsigned int*)g,
      (__attribute__((address_space(3))) unsigned int*)l, 16, 0, 0);
}

// ================= pre-pass 1: A fp32 -> fp16 =================
__global__ __launch_bounds__(256) void cvt_a(const float* __restrict__ A,
                                             _Float16* __restrict__ Ah) {
  const size_t i = ((size_t)blockIdx.x * 256 + threadIdx.x) * 8;
  f32x4 v0 = *(const f32x4*)(A + i);
  f32x4 v1 = *(const f32x4*)(A + i + 4);
  union { f16x2 h2[4]; f16x8 v; } u;
  u.h2[0] = pk16(v0[0], v0[1]);
  u.h2[1] = pk16(v0[2], v0[3]);
  u.h2[2] = pk16(v1[0], v1[1]);
  u.h2[3] = pk16(v1[2], v1[3]);
  *(f16x8*)(Ah + i) = u.v;
}

// ====== pre-pass 2: dequant Q[k][n] -> W^T[n][k] fp16 (64x64 LDS transpose) ======
__global__ __launch_bounds__(256) void deq_wt(const int* __restrict__ Q,
                                              const float* __restrict__ S,
                                              const float* __restrict__ Z,
                                              _Float16* __restrict__ WT) {
  __shared__ _Float16 T[64][72];  // [n][k], stride 144B (16B-aligned rows)
  const int tid = threadIdx.x;
  const int n0 = ((int)blockIdx.x & 63) * 64;
  const int k0 = ((int)blockIdx.x >> 6) * 64;
  const int g = k0 >> 7;  // GS=128, 64|k0 -> group constant per tile

  const int c4 = (tid & 15) * 4;
  f32x4 s4 = *(const f32x4*)(S + (size_t)g * NN + n0 + c4);
  f32x4 z4 = *(const f32x4*)(Z + (size_t)g * NN + n0 + c4);
#pragma unroll
  for (int p = 0; p < 4; ++p) {
    const int r = (tid >> 4) + p * 16;
    i32x4 q = *(const i32x4*)(Q + (size_t)(k0 + r) * NN + n0 + c4);
#pragma unroll
    for (int j = 0; j < 4; ++j)
      T[c4 + j][r] = (_Float16)(((float)q[j] - z4[j]) * s4[j]);
  }
  __syncthreads();
  const int n = tid >> 2;
  const int kc = (tid & 3) * 16;
  f16x8 w0 = *(const f16x8*)&T[n][kc];
  f16x8 w1 = *(const f16x8*)&T[n][kc + 8];
  _Float16* dst = WT + (size_t)(n0 + n) * KK + k0 + kc;
  *(f16x8*)dst = w0;
  *(f16x8*)(dst + 8) = w1;
}

// ======== main GEMM: m97 structure + m173 pre-swizzled-source staging ========
// LDS layout: byte(row,kb) = row*128 + (kb ^ ((row&7)<<4))
//   write side: gload_lds dest is lane-linear; the per-lane GLOBAL source chunk
//               is (lane&7)^(lane>>3), so the DMA lands data in the XOR layout.
//   read side:  fragment k-offset XORed with (lr&7)<<4 (R5-verified, 0 conflicts).
__global__ __launch_bounds__(256, 2) void gemm16(const _Float16* __restrict__ Ah,
                                                 const _Float16* __restrict__ WT,
                                                 float* __restrict__ C) {
  __shared__ __align__(16) _Float16 AsBuf[2][BM * BK];
  __shared__ __align__(16) _Float16 BsBuf[2][BN * BK];

  const int tid = threadIdx.x;
  const int lane = tid & 63;
  const int wid = tid >> 6;

  // bijective XCD swizzle (nwg=1024 % 8 == 0); m fast-varying
  const int nwg = (int)gridDim.x;
  const int bid0 = (int)blockIdx.x;
  const int wg = (bid0 & 7) * (nwg >> 3) + (bid0 >> 3);
  const int m0 = (wg & 31) * BM;
  const int n0 = (wg >> 5) * BN;

  // staging: wave w, pass p covers rows p*32 + w*8 + (lane>>3); row&7 == lane>>3
  const int st_row = wid * 8 + (lane >> 3);
  const int st_k = (((lane & 7) ^ (lane >> 3)) * 8);  // pre-swizzled source chunk
  const _Float16* a_src = Ah + (size_t)(m0 + st_row) * KK + st_k;
  const _Float16* b_src = WT + (size_t)(n0 + st_row) * KK + st_k;

  // compute-side fragment addressing (swizzled reads)
  const int wm = wid >> 1, wn = wid & 1;
  const int lr = lane & 15, lg = lane >> 4;
  const int rx = (lr & 7) << 4;  // row&7 == lr&7 for fragment rows
  int a_row[4], b_row[4], koffx[2];
#pragma unroll
  for (int f = 0; f < 4; ++f) {
    a_row[f] = (wm * 64 + f * 16 + lr) * (BK * 2);
    b_row[f] = (wn * 64 + f * 16 + lr) * (BK * 2);
  }
#pragma unroll
  for (int ks = 0; ks < 2; ++ks)
    koffx[ks] = ((ks * 32 + lg * 8) * 2) ^ rx;

  f32x4 acc[4][4];
#pragma unroll
  for (int i = 0; i < 4; ++i)
#pragma unroll
    for (int j = 0; j < 4; ++j) acc[i][j] = (f32x4){0.f, 0.f, 0.f, 0.f};

  auto stage = [&](int c, int t) {
    char* abase = (char*)&AsBuf[c][0] + wid * 1024;
    char* bbase = (char*)&BsBuf[c][0] + wid * 1024;
    const _Float16* ap = a_src + (size_t)t * BK;
    const _Float16* bp = b_src + (size_t)t * BK;
#pragma unroll
    for (int p = 0; p < 4; ++p)
      gload_lds16(ap + (size_t)p * 32 * KK, abase + p * 4096);
#pragma unroll
    for (int p = 0; p < 4; ++p)
      gload_lds16(bp + (size_t)p * 32 * KK, bbase + p * 4096);
  };

  // prologue
  stage(0, 0);
  asm volatile("s_waitcnt vmcnt(0)" ::: "memory");
  __syncthreads();

  for (int t = 0; t < NT; ++t) {
    const int c = t & 1;
    if (t + 1 < NT) stage(c ^ 1, t + 1);  // DMA overlaps MFMA below

    {
      const char* as = (const char*)&AsBuf[c][0];
      const char* bs = (const char*)&BsBuf[c][0];
#pragma unroll
      for (int ks = 0; ks < 2; ++ks) {
        f16x8 af[4], bfr[4];
#pragma unroll
        for (int f = 0; f < 4; ++f) {
          af[f] = *(const f16x8*)(as + (a_row[f] + koffx[ks]));
          bfr[f] = *(const f16x8*)(bs + (b_row[f] + koffx[ks]));
        }
#pragma unroll
        for (int i = 0; i < 4; ++i)
#pragma unroll
          for (int j = 0; j < 4; ++j)
            acc[i][j] = __builtin_amdgcn_mfma_f32_16x16x32_f16(
                af[i], bfr[j], acc[i][j], 0, 0, 0);
      }
    }

    asm volatile("s_waitcnt vmcnt(0)" ::: "memory");
    __syncthreads();
  }

  // epilogue: C/D col=lane&15, row=(lane>>4)*4+reg
#pragma unroll
  for (int i = 0; i < 4; ++i) {
    const int row0 = m0 + wm * 64 + i * 16 + lg * 4;
#pragma unroll
    for (int j = 0; j < 4; ++j) {
      const int col = n0 + wn * 64 + j * 16 + lr;
#pragma unroll
      for (int r = 0; r < 4; ++r)
        C[(size_t)(row0 + r) * NN + col] = acc[i][j][r];
    }
  }
}

// ================= fallback: Round-5 fused kernel (proven) =================
__global__ __launch_bounds__(256, 2) void wq_gemm(
    const float* __restrict__ A, const int* __restrict__ Q,
    const float* __restrict__ S, const float* __restrict__ Z,
    float* __restrict__ C) {
  __shared__ __align__(16) _Float16 AsBuf[2][BM * BK];
  __shared__ __align__(16) _Float16 BsBuf[2][BN * BK];

  const int tid = threadIdx.x;
  const int lane = tid & 63;
  const int wid = tid >> 6;

  const int nwg = (int)gridDim.x;
  const int bid0 = (int)blockIdx.x;
  const int wg = (bid0 & 7) * (nwg >> 3) + (bid0 >> 3);
  const int m0 = (wg & 31) * BM;
  const int n0 = (wg >> 5) * BN;

  const int a_m = tid >> 3;
  const int a_k = (tid & 7) * 8;
  const float* a_src = A + (size_t)(m0 + a_m) * KK + a_k;
  const int a_woff = a_m * (BK * 2) + ((a_k * 2) ^ ((a_m & 7) << 4));

  const int n_loc = tid & 127;
  const int kk0 = (tid >> 7) * 32;
  const int* q_src = Q + (size_t)kk0 * NN + (n0 + n_loc);
  const float* s_src = S + (n0 + n_loc);
  const float* z_src = Z + (n0 + n_loc);
  int bw_off[4];
#pragma unroll
  for (int j = 0; j < 4; ++j)
    bw_off[j] = n_loc * (BK * 2) + (((kk0 + j * 8) * 2) ^ ((n_loc & 7) << 4));

  const int wm = wid >> 1, wn = wid & 1;
  const int lr = lane & 15, lg = lane >> 4;
  const int rx = (lr & 7) << 4;
  int a_row[4], b_row[4], koffx[2];
#pragma unroll
  for (int f = 0; f < 4; ++f) {
    a_row[f] = (wm * 64 + f * 16 + lr) * (BK * 2);
    b_row[f] = (wn * 64 + f * 16 + lr) * (BK * 2);
  }
#pragma unroll
  for (int ks = 0; ks < 2; ++ks)
    koffx[ks] = ((ks * 32 + lg * 8) * 2) ^ rx;

  f32x4 acc[4][4];
#pragma unroll
  for (int i = 0; i < 4; ++i)
#pragma unroll
    for (int j = 0; j < 4; ++j) acc[i][j] = (f32x4){0.f, 0.f, 0.f, 0.f};

  f32x4 av[8];
  int qv[32];
  float sf, bf;

  auto stage_load = [&](int t) {
    const float* ap = a_src + (size_t)t * BK;
#pragma unroll
    for (int p = 0; p < 4; ++p) {
      av[p * 2] = *(const f32x4*)(ap + (size_t)p * 32 * KK);
      av[p * 2 + 1] = *(const f32x4*)(ap + (size_t)p * 32 * KK + 4);
    }
    const int* qp = q_src + (size_t)t * BK * NN;
#pragma unroll
    for (int i = 0; i < 32; ++i) qv[i] = qp[(size_t)i * NN];
    const int g = t >> 1;
    sf = s_src[(size_t)g * NN];
    bf = -z_src[(size_t)g * NN] * sf;
  };

  auto stage_write = [&](int c) {
    char* as = (char*)&AsBuf[c][0];
#pragma unroll
    for (int p = 0; p < 4; ++p) {
      union { f16x2 h2[4]; f16x8 v; } u;
      f32x4 v0 = av[p * 2], v1 = av[p * 2 + 1];
      u.h2[0] = pk16(v0[0], v0[1]);
      u.h2[1] = pk16(v0[2], v0[3]);
      u.h2[2] = pk16(v1[0], v1[1]);
      u.h2[3] = pk16(v1[2], v1[3]);
      *(f16x8*)(as + a_woff + p * 4096) = u.v;
    }
    char* bs = (char*)&BsBuf[c][0];
#pragma unroll
    for (int j = 0; j < 4; ++j) {
      union { f16x2 h2[4]; f16x8 v; } u;
#pragma unroll
      for (int p = 0; p < 4; ++p) {
        float w0 = (float)qv[j * 8 + p * 2] * sf + bf;
        float w1 = (float)qv[j * 8 + p * 2 + 1] * sf + bf;
        u.h2[p] = pk16(w0, w1);
      }
      *(f16x8*)(bs + bw_off[j]) = u.v;
    }
  };

  stage_load(0);
  stage_write(0);
  __syncthreads();

  for (int t = 0; t < NT; ++t) {
    const int c = t & 1;
    if (t + 1 < NT) stage_load(t + 1);

    {
      const char* as = (const char*)&AsBuf[c][0];
      const char* bs = (const char*)&BsBuf[c][0];
#pragma unroll
      for (int ks = 0; ks < 2; ++ks) {
        f16x8 af[4], bfr[4];
#pragma unroll
        for (int f = 0; f < 4; ++f) {
          af[f] = *(const f16x8*)(as + (a_row[f] + koffx[ks]));
          bfr[f] = *(const f16x8*)(bs + (b_row[f] + koffx[ks]));
        }
#pragma unroll
        for (int i = 0; i < 4; ++i)
#pragma unroll
          for (int j = 0; j < 4; ++j)
            acc[i][j] = __builtin_amdgcn_mfma_f32_16x16x32_f16(
                af[i], bfr[j], acc[i][j], 0, 0, 0);
      }
    }

    if (t + 1 < NT) stage_write(c ^ 1);
    __syncthreads();
  }

#pragma unroll
  for (int i = 0; i < 4; ++i) {
    const int row0 = m0 + wm * 64 + i * 16 + lg * 4;
#pragma unroll
    for (int j = 0; j < 4; ++j) {
      const int col = n0 + wn * 64 + j * 16 + lr;
#pragma unroll
      for (int r = 0; r < 4; ++r)
        C[(size_t)(row0 + r) * NN + col] = acc[i][j][r];
    }
  }
}

extern "C" void kernel_launch(void* const* d_in, const int* in_sizes, int n_in,
                              void* d_out, int out_size, void* d_ws, size_t ws_size,
                              hipStream_t stream) {
  const float* A = (const float*)d_in[0];
  const int* Q = (const int*)d_in[1];
  const float* S = (const float*)d_in[2];
  const float* Z = (const float*)d_in[3];
  float* C = (float*)d_out;

  const size_t needA = (size_t)MM * KK * sizeof(_Float16);
  const size_t needW = (size_t)KK * NN * sizeof(_Float16);
  if (ws_size >= needA + needW) {
    _Float16* Ah = (_Float16*)d_ws;
    _Float16* WT = (_Float16*)((char*)d_ws + needA);
    cvt_a<<<dim3(MM * KK / (8 * 256)), dim3(256), 0, stream>>>(A, Ah);
    deq_wt<<<dim3((KK / 64) * (NN / 64)), dim3(256), 0, stream>>>(Q, S, Z, WT);
    gemm16<<<dim3((MM / BM) * (NN / BN)), dim3(256), 0, stream>>>(Ah, WT, C);
  } else {
    wq_gemm<<<dim3((MM / BM) * (NN / BN)), dim3(256), 0, stream>>>(A, Q, S, Z, C);
  }
}

// Round 9
// 174.074 us; speedup vs baseline: 2.4133x; 1.2719x over previous
//
#include <hip/hip_runtime.h>

#define MM 4096
#define NN 4096
#define KK 4096
#define NT (KK / 64)

typedef __attribute__((ext_vector_type(8))) _Float16 f16x8;
typedef __attribute__((ext_vector_type(2))) _Float16 f16x2;
typedef __attribute__((ext_vector_type(4))) float f32x4;
typedef __attribute__((ext_vector_type(4))) int i32x4;

__device__ __forceinline__ f16x2 pk16(float a, float b) {
  return __builtin_bit_cast(f16x2, __builtin_amdgcn_cvt_pkrtz(a, b));
}

__device__ __forceinline__ void gload_lds16(const void* g, void* l) {
  __builtin_amdgcn_global_load_lds(
      (const __attribute__((address_space(1))) unsigned int*)g,
      (__attribute__((address_space(3))) unsigned int*)l, 16, 0, 0);
}

// ================= pre-pass 1: A fp32 -> fp16 =================
__global__ __launch_bounds__(256) void cvt_a(const float* __restrict__ A,
                                             _Float16* __restrict__ Ah) {
  const size_t i = ((size_t)blockIdx.x * 256 + threadIdx.x) * 8;
  f32x4 v0 = *(const f32x4*)(A + i);
  f32x4 v1 = *(const f32x4*)(A + i + 4);
  union { f16x2 h2[4]; f16x8 v; } u;
  u.h2[0] = pk16(v0[0], v0[1]);
  u.h2[1] = pk16(v0[2], v0[3]);
  u.h2[2] = pk16(v1[0], v1[1]);
  u.h2[3] = pk16(v1[2], v1[3]);
  *(f16x8*)(Ah + i) = u.v;
}

// ====== pre-pass 2: dequant Q[k][n] -> W^T[n][k] fp16 (64x64 LDS transpose) ======
__global__ __launch_bounds__(256) void deq_wt(const int* __restrict__ Q,
                                              const float* __restrict__ S,
                                              const float* __restrict__ Z,
                                              _Float16* __restrict__ WT) {
  __shared__ _Float16 T[64][72];
  const int tid = threadIdx.x;
  const int n0 = ((int)blockIdx.x & 63) * 64;
  const int k0 = ((int)blockIdx.x >> 6) * 64;
  const int g = k0 >> 7;

  const int c4 = (tid & 15) * 4;
  f32x4 s4 = *(const f32x4*)(S + (size_t)g * NN + n0 + c4);
  f32x4 z4 = *(const f32x4*)(Z + (size_t)g * NN + n0 + c4);
#pragma unroll
  for (int p = 0; p < 4; ++p) {
    const int r = (tid >> 4) + p * 16;
    i32x4 q = *(const i32x4*)(Q + (size_t)(k0 + r) * NN + n0 + c4);
#pragma unroll
    for (int j = 0; j < 4; ++j)
      T[c4 + j][r] = (_Float16)(((float)q[j] - z4[j]) * s4[j]);
  }
  __syncthreads();
  const int n = tid >> 2;
  const int kc = (tid & 3) * 16;
  f16x8 w0 = *(const f16x8*)&T[n][kc];
  f16x8 w1 = *(const f16x8*)&T[n][kc + 8];
  _Float16* dst = WT + (size_t)(n0 + n) * KK + k0 + kc;
  *(f16x8*)dst = w0;
  *(f16x8*)(dst + 8) = w1;
}

// ======== main GEMM: 256x256 tile, 8 waves, 8-phase counted-vmcnt schedule ========
// LDS: As/Bs [dbuf][half][128 rows][64 k] fp16, XOR layout via pre-swizzled source:
//   LDS chunk c of row r holds global k-chunk c ^ (r&7); frag reads XOR (lr&7)<<4.
// Phase ledger (per iteration i; tiles T=2i in buf0, T+1 in buf1; snake (h,g)):
//   P0 read A(0,h0)+B(0,g0) mma(0,0)  stage buf1.A1<-T+1
//   P1 read B(0,g1)         mma(0,1)  stage buf1.B0<-T+1
//   P2 read A(0,h1)         mma(1,1)  stage buf0.A0<-T+2
//   P3 read B(0,g0)         mma(1,0)  stage buf0.B1<-T+2   vmcnt(4) pre-barrier
//   P4 read A(1,h0)+B(1,g0) mma(0,0)  stage buf0.A1<-T+2
//   P5 read B(1,g1)         mma(0,1)  stage buf0.B0<-T+2
//   P6 read A(1,h1)         mma(1,1)  stage buf1.A0<-T+3
//   P7 read B(1,g0)         mma(1,0)  stage buf1.B1<-T+3   vmcnt(4) pre-barrier
// Every restaged half is dead >=1 phase (barrier-separated) before its stage slot;
// vmcnt(4) = 2 stages x 2 loads outstanding drains the consumed tile's 4 halves.

#define READ_A(BUF, H)                                                   \
  { const char* base_ = (const char*)&As[BUF][H][0];                     \
    _Pragma("unroll") for (int ks = 0; ks < 2; ++ks)                     \
    _Pragma("unroll") for (int f = 0; f < 4; ++f)                        \
      af[ks][f] = *(const f16x8*)(base_ + a_rb[f] + koffx[ks]); }

#define READ_B(BUF, G)                                                   \
  { const char* base_ = (const char*)&Bs[BUF][G][0];                     \
    _Pragma("unroll") for (int ks = 0; ks < 2; ++ks)                     \
    _Pragma("unroll") for (int e = 0; e < 2; ++e)                        \
      bf[ks][e] = *(const f16x8*)(base_ + b_rb[e] + koffx[ks]); }

#define STAGE_A(BUF, H, T)                                               \
  { const _Float16* src_ = Ah + a_srow[H] + (size_t)(T) * 64;            \
    char* dst_ = (char*)&As[BUF][H][0] + wid * 1024;                     \
    gload_lds16(src_, dst_);                                             \
    gload_lds16(src_ + (size_t)64 * KK, dst_ + 8192); }

#define STAGE_B(BUF, G, T)                                               \
  { const _Float16* src_ = WT + b_srow[G] + (size_t)(T) * 64;            \
    char* dst_ = (char*)&Bs[BUF][G][0] + wid * 1024;                     \
    gload_lds16(src_, dst_);                                             \
    gload_lds16(src_ + (size_t)64 * KK, dst_ + 8192); }

#define MMA_Q(H, G)                                                      \
  _Pragma("unroll") for (int ks = 0; ks < 2; ++ks)                       \
  _Pragma("unroll") for (int f = 0; f < 4; ++f)                          \
  _Pragma("unroll") for (int e = 0; e < 2; ++e)                          \
    acc[H][f][G][e] = __builtin_amdgcn_mfma_f32_16x16x32_f16(            \
        af[ks][f], bf[ks][e], acc[H][f][G][e], 0, 0, 0);

#define PHASE_TAIL(H, G)                                                 \
  __builtin_amdgcn_s_barrier();                                          \
  asm volatile("s_waitcnt lgkmcnt(0)" ::: "memory");                     \
  __builtin_amdgcn_sched_barrier(0);                                     \
  __builtin_amdgcn_s_setprio(1);                                         \
  MMA_Q(H, G);                                                           \
  __builtin_amdgcn_s_setprio(0);                                         \
  __builtin_amdgcn_s_barrier();

#define PHASE_TAIL_V(H, G)                                               \
  __builtin_amdgcn_s_barrier();                                          \
  asm volatile("s_waitcnt lgkmcnt(0)" ::: "memory");                     \
  __builtin_amdgcn_sched_barrier(0);                                     \
  __builtin_amdgcn_s_setprio(1);                                         \
  MMA_Q(H, G);                                                           \
  __builtin_amdgcn_s_setprio(0);                                         \
  asm volatile("s_waitcnt vmcnt(4)" ::: "memory");                       \
  __builtin_amdgcn_sched_barrier(0);                                     \
  __builtin_amdgcn_s_barrier();

__global__ __launch_bounds__(512, 2) void gemm256(const _Float16* __restrict__ Ah,
                                                  const _Float16* __restrict__ WT,
                                                  float* __restrict__ C) {
  __shared__ __align__(16) _Float16 As[2][2][128 * 64];  // [buf][half][r][k]
  __shared__ __align__(16) _Float16 Bs[2][2][128 * 64];

  const int tid = threadIdx.x;
  const int lane = tid & 63;
  const int wid = tid >> 6;

  // bijective XCD swizzle (nwg=256 % 8 == 0); m fast-varying
  const int nwg = (int)gridDim.x;
  const int bid0 = (int)blockIdx.x;
  const int wg = (bid0 & 7) * (nwg >> 3) + (bid0 >> 3);
  const int m0 = (wg & 15) * 256;
  const int n0 = (wg >> 4) * 256;

  // staging: wave stages 8 rows/pass, 2 passes per half-tile; source pre-swizzled
  const int st_row = wid * 8 + (lane >> 3);
  const int st_k = ((lane & 7) ^ (lane >> 3)) * 8;
  size_t a_srow[2], b_srow[2];
#pragma unroll
  for (int h = 0; h < 2; ++h) {
    a_srow[h] = (size_t)(m0 + h * 128 + st_row) * KK + st_k;
    b_srow[h] = (size_t)(n0 + h * 128 + st_row) * KK + st_k;
  }

  // compute-side fragment addressing
  const int wm = wid >> 2, wn = wid & 3;
  const int lr = lane & 15, lg = lane >> 4;
  int a_rb[4], b_rb[2], koffx[2];
#pragma unroll
  for (int f = 0; f < 4; ++f) a_rb[f] = (wm * 64 + f * 16 + lr) * 128;
#pragma unroll
  for (int e = 0; e < 2; ++e) b_rb[e] = (wn * 32 + e * 16 + lr) * 128;
#pragma unroll
  for (int ks = 0; ks < 2; ++ks)
    koffx[ks] = ((ks * 32 + lg * 8) * 2) ^ ((lr & 7) << 4);

  f32x4 acc[2][4][2][2];
#pragma unroll
  for (int h = 0; h < 2; ++h)
#pragma unroll
    for (int f = 0; f < 4; ++f)
#pragma unroll
      for (int g = 0; g < 2; ++g)
#pragma unroll
        for (int e = 0; e < 2; ++e) acc[h][f][g][e] = (f32x4){0.f, 0.f, 0.f, 0.f};

  f16x8 af[2][4], bf[2][2];

  // ---- prologue: buf0 <- tile 0 (4 halves), buf1.A0/B1 <- tile 1 ----
  STAGE_A(0, 0, 0);
  STAGE_B(0, 1, 0);
  STAGE_A(0, 1, 0);
  STAGE_B(0, 0, 0);
  STAGE_A(1, 0, 1);
  STAGE_B(1, 1, 1);
  asm volatile("s_waitcnt vmcnt(4)" ::: "memory");
  __builtin_amdgcn_s_barrier();

  // ---- main loop: 2 K-tiles per iteration, 8 phases ----
  for (int i = 0; i < NT / 2; ++i) {
    const int t1 = 2 * i + 1;
    const int t2 = (2 * i + 2) & (NT - 1);  // wrap on last iter (harmless restage)
    const int t3 = (2 * i + 3) & (NT - 1);

    READ_A(0, 0); READ_B(0, 0); STAGE_A(1, 1, t1);
    PHASE_TAIL(0, 0);
    READ_B(0, 1); STAGE_B(1, 0, t1);
    PHASE_TAIL(0, 1);
    READ_A(0, 1); STAGE_A(0, 0, t2);
    PHASE_TAIL(1, 1);
    READ_B(0, 0); STAGE_B(0, 1, t2);
    PHASE_TAIL_V(1, 0);

    READ_A(1, 0); READ_B(1, 0); STAGE_A(0, 1, t2);
    PHASE_TAIL(0, 0);
    READ_B(1, 1); STAGE_B(0, 0, t2);
    PHASE_TAIL(0, 1);
    READ_A(1, 1); STAGE_A(1, 0, t3);
    PHASE_TAIL(1, 1);
    READ_B(1, 0); STAGE_B(1, 1, t3);
    PHASE_TAIL_V(1, 0);
  }

  // ---- epilogue: C/D col=lane&15, row=(lane>>4)*4+reg ----
#pragma unroll
  for (int h = 0; h < 2; ++h)
#pragma unroll
    for (int f = 0; f < 4; ++f) {
      const int row0 = m0 + h * 128 + wm * 64 + f * 16 + lg * 4;
#pragma unroll
      for (int g = 0; g < 2; ++g)
#pragma unroll
        for (int e = 0; e < 2; ++e) {
          const int col = n0 + g * 128 + wn * 32 + e * 16 + lr;
#pragma unroll
          for (int r = 0; r < 4; ++r)
            C[(size_t)(row0 + r) * NN + col] = acc[h][f][g][e][r];
        }
    }
}

// ================= fallback: Round-5 fused kernel (proven) =================
__global__ __launch_bounds__(256, 2) void wq_gemm(
    const float* __restrict__ A, const int* __restrict__ Q,
    const float* __restrict__ S, const float* __restrict__ Z,
    float* __restrict__ C) {
  __shared__ __align__(16) _Float16 AsBuf[2][128 * 64];
  __shared__ __align__(16) _Float16 BsBuf[2][128 * 64];

  const int tid = threadIdx.x;
  const int lane = tid & 63;
  const int wid = tid >> 6;

  const int nwg = (int)gridDim.x;
  const int bid0 = (int)blockIdx.x;
  const int wg = (bid0 & 7) * (nwg >> 3) + (bid0 >> 3);
  const int m0 = (wg & 31) * 128;
  const int n0 = (wg >> 5) * 128;

  const int a_m = tid >> 3;
  const int a_k = (tid & 7) * 8;
  const float* a_src = A + (size_t)(m0 + a_m) * KK + a_k;
  const int a_woff = a_m * 128 + ((a_k * 2) ^ ((a_m & 7) << 4));

  const int n_loc = tid & 127;
  const int kk0 = (tid >> 7) * 32;
  const int* q_src = Q + (size_t)kk0 * NN + (n0 + n_loc);
  const float* s_src = S + (n0 + n_loc);
  const float* z_src = Z + (n0 + n_loc);
  int bw_off[4];
#pragma unroll
  for (int j = 0; j < 4; ++j)
    bw_off[j] = n_loc * 128 + (((kk0 + j * 8) * 2) ^ ((n_loc & 7) << 4));

  const int wm = wid >> 1, wn = wid & 1;
  const int lr = lane & 15, lg = lane >> 4;
  const int rx = (lr & 7) << 4;
  int a_row[4], b_row[4], koffx[2];
#pragma unroll
  for (int f = 0; f < 4; ++f) {
    a_row[f] = (wm * 64 + f * 16 + lr) * 128;
    b_row[f] = (wn * 64 + f * 16 + lr) * 128;
  }
#pragma unroll
  for (int ks = 0; ks < 2; ++ks)
    koffx[ks] = ((ks * 32 + lg * 8) * 2) ^ rx;

  f32x4 acc[4][4];
#pragma unroll
  for (int i = 0; i < 4; ++i)
#pragma unroll
    for (int j = 0; j < 4; ++j) acc[i][j] = (f32x4){0.f, 0.f, 0.f, 0.f};

  f32x4 av[8];
  int qv[32];
  float sf, bfv;

  auto stage_load = [&](int t) {
    const float* ap = a_src + (size_t)t * 64;
#pragma unroll
    for (int p = 0; p < 4; ++p) {
      av[p * 2] = *(const f32x4*)(ap + (size_t)p * 32 * KK);
      av[p * 2 + 1] = *(const f32x4*)(ap + (size_t)p * 32 * KK + 4);
    }
    const int* qp = q_src + (size_t)t * 64 * NN;
#pragma unroll
    for (int i = 0; i < 32; ++i) qv[i] = qp[(size_t)i * NN];
    const int g = t >> 1;
    sf = s_src[(size_t)g * NN];
    bfv = -z_src[(size_t)g * NN] * sf;
  };

  auto stage_write = [&](int c) {
    char* as = (char*)&AsBuf[c][0];
#pragma unroll
    for (int p = 0; p < 4; ++p) {
      union { f16x2 h2[4]; f16x8 v; } u;
      f32x4 v0 = av[p * 2], v1 = av[p * 2 + 1];
      u.h2[0] = pk16(v0[0], v0[1]);
      u.h2[1] = pk16(v0[2], v0[3]);
      u.h2[2] = pk16(v1[0], v1[1]);
      u.h2[3] = pk16(v1[2], v1[3]);
      *(f16x8*)(as + a_woff + p * 4096) = u.v;
    }
    char* bs = (char*)&BsBuf[c][0];
#pragma unroll
    for (int j = 0; j < 4; ++j) {
      union { f16x2 h2[4]; f16x8 v; } u;
#pragma unroll
      for (int p = 0; p < 4; ++p) {
        float w0 = (float)qv[j * 8 + p * 2] * sf + bfv;
        float w1 = (float)qv[j * 8 + p * 2 + 1] * sf + bfv;
        u.h2[p] = pk16(w0, w1);
      }
      *(f16x8*)(bs + bw_off[j]) = u.v;
    }
  };

  stage_load(0);
  stage_write(0);
  __syncthreads();

  for (int t = 0; t < NT; ++t) {
    const int c = t & 1;
    if (t + 1 < NT) stage_load(t + 1);
    {
      const char* as = (const char*)&AsBuf[c][0];
      const char* bs = (const char*)&BsBuf[c][0];
#pragma unroll
      for (int ks = 0; ks < 2; ++ks) {
        f16x8 a4[4], b4[4];
#pragma unroll
        for (int f = 0; f < 4; ++f) {
          a4[f] = *(const f16x8*)(as + (a_row[f] + koffx[ks]));
          b4[f] = *(const f16x8*)(bs + (b_row[f] + koffx[ks]));
        }
#pragma unroll
        for (int i = 0; i < 4; ++i)
#pragma unroll
          for (int j = 0; j < 4; ++j)
            acc[i][j] = __builtin_amdgcn_mfma_f32_16x16x32_f16(
                a4[i], b4[j], acc[i][j], 0, 0, 0);
      }
    }
    if (t + 1 < NT) stage_write(c ^ 1);
    __syncthreads();
  }

#pragma unroll
  for (int i = 0; i < 4; ++i) {
    const int row0 = m0 + wm * 64 + i * 16 + lg * 4;
#pragma unroll
    for (int j = 0; j < 4; ++j) {
      const int col = n0 + wn * 64 + j * 16 + lr;
#pragma unroll
      for (int r = 0; r < 4; ++r)
        C[(size_t)(row0 + r) * NN + col] = acc[i][j][r];
    }
  }
}

extern "C" void kernel_launch(void* const* d_in, const int* in_sizes, int n_in,
                              void* d_out, int out_size, void* d_ws, size_t ws_size,
                              hipStream_t stream) {
  const float* A = (const float*)d_in[0];
  const int* Q = (const int*)d_in[1];
  const float* S = (const float*)d_in[2];
  const float* Z = (const float*)d_in[3];
  float* C = (float*)d_out;

  const size_t needA = (size_t)MM * KK * sizeof(_Float16);
  const size_t needW = (size_t)KK * NN * sizeof(_Float16);
  if (ws_size >= needA + needW) {
    _Float16* Ah = (_Float16*)d_ws;
    _Float16* WT = (_Float16*)((char*)d_ws + needA);
    cvt_a<<<dim3(MM * KK / (8 * 256)), dim3(256), 0, stream>>>(A, Ah);
    deq_wt<<<dim3((KK / 64) * (NN / 64)), dim3(256), 0, stream>>>(Q, S, Z, WT);
    gemm256<<<dim3((MM / 256) * (NN / 256)), dim3(512), 0, stream>>>(Ah, WT, C);
  } else {
    wq_gemm<<<dim3((MM / 128) * (NN / 128)), dim3(256), 0, stream>>>(A, Q, S, Z, C);
  }
}